// Round 1
// 111.968 us; speedup vs baseline: 1.0217x; 1.0217x over previous
//
#include <hip/hip_runtime.h>

// Tucker reconstruction + gather, bf16 MFMA pipeline (3 dispatches):
//   K01f: [f1,f2 -> bf16 cvt blocks]  +  [fused mode-0 + transpose:
//          A1t[i][c][b] = sum_a f0[i][a]*core[a][b][c], written directly]
//   K2  : A2[(i*768+j)][c] = sum_b f1[j][b]*A1t[i][c][b]   (MFMA bf16)
//         run as ONE flattened GEMM: M=768 (j), N=10240 ((i,c)), K=256 (b)
//   K3  : out[n][k] = sum_c A2[ids[n]][c]*f2[k][c]         (MFMA bf16, gathered)
// table row index == i*768+j == A2 row; ids < 30522 <= 30720 so gather is in-range.
// Round-10 change: K2/K3 moved from 64x64 tiles (343-TF-class, 4 MFMA/wave per
// barrier pair) to m97-structure 128x128 tiles, BK=32, 4x4 frags/wave
// (16 MFMA/wave per barrier pair) -- same global_load_lds width-16 staging.
// Round-9 lesson: 16x16-tile mode-0 with 256-KB-stride core loads at 1
// wave/SIMD regressed 13 us -- core re-reads were L2-free all along.
// Round-7 lesson: serial bucket block costs ~20 us.
// Round-5 lesson: hipLaunchCooperativeKernel silently fails in this harness.

#define A_DIM 40
#define BC 65536   // 256*256
#define C_DIM 256
#define HID 768

typedef __attribute__((ext_vector_type(8))) short short8;   // 8 x bf16 (4 VGPR)
typedef __attribute__((ext_vector_type(4))) float floatx4;  // MFMA C/D

#define AS1 __attribute__((address_space(1)))
#define AS3 __attribute__((address_space(3)))

// async 16B global->LDS DMA: per-lane global addr (gather OK), wave-uniform LDS
// base; HW writes lane i at base + i*16.
__device__ __forceinline__ void gl2lds16(const unsigned short* g, unsigned short* l) {
    __builtin_amdgcn_global_load_lds((const AS1 unsigned int*)g, (AS3 unsigned int*)l,
                                     16, 0, 0);
}

__device__ __forceinline__ unsigned short f2bf(float f) {
    unsigned int u = __builtin_bit_cast(unsigned int, f);
    u += 0x7FFFu + ((u >> 16) & 1u);   // round-to-nearest-even
    return (unsigned short)(u >> 16);
}

// ---------------- K01f: fused cvt + mode-0 + transpose ----------------------
// blocks [0,512): mode-0+transpose. bid: ig=bid>>6 (i0=ig*5), tile=bid&63
//   (b0=(tile>>3)*32, c0=(tile&7)*32). Thread: 2x2 patch, 5 i accumulators.
// blocks [512,896): f1/f2 -> bf16 convert.
__global__ __launch_bounds__(256) void k01_fused(const float* __restrict__ core,
                                                 const float* __restrict__ f0,
                                                 const float* __restrict__ f1,
                                                 const float* __restrict__ f2,
                                                 unsigned short* __restrict__ A1t,
                                                 unsigned short* __restrict__ f1b,
                                                 unsigned short* __restrict__ f2b) {
    const int bid = blockIdx.x;
    const int tid = threadIdx.x;
    if (bid < 512) {
        __shared__ float f0s[200];                     // f0 rows i0..i0+4
        __shared__ unsigned short tt[32 * 34];         // transposed tile [c][b], pitch 34
        const int i0 = (bid >> 6) * 5;
        const int tile = bid & 63;
        const int b0 = (tile >> 3) * 32;
        const int c0 = (tile & 7) * 32;
        if (tid < 200) f0s[tid] = f0[i0 * A_DIM + tid];
        __syncthreads();

        const int pb = (tid >> 4) * 2;                 // local b of 2x2 patch
        const int pc = (tid & 15) * 2;                 // local c
        float acc[5][4];                               // [ii][{b0c0,b0c1,b1c0,b1c1}]
#pragma unroll
        for (int ii = 0; ii < 5; ++ii)
#pragma unroll
            for (int e = 0; e < 4; ++e) acc[ii][e] = 0.f;

        const float* cp0 = core + (b0 + pb) * 256 + (c0 + pc);
        for (int a = 0; a < A_DIM; ++a) {
            const float* cp = cp0 + a * BC;
            const float2 r0 = *(const float2*)cp;          // [pb  ][pc..pc+1]
            const float2 r1 = *(const float2*)(cp + 256);  // [pb+1][pc..pc+1]
#pragma unroll
            for (int ii = 0; ii < 5; ++ii) {
                const float fa = f0s[ii * A_DIM + a];
                acc[ii][0] += fa * r0.x;   // (b=pb,   c=pc)
                acc[ii][1] += fa * r0.y;   // (b=pb,   c=pc+1)
                acc[ii][2] += fa * r1.x;   // (b=pb+1, c=pc)
                acc[ii][3] += fa * r1.y;   // (b=pb+1, c=pc+1)
            }
        }
        const int rc = tid >> 3;                       // read row (c) 0..31
        const int rb4 = (tid & 7) * 4;                 // read col (b) group of 4
#pragma unroll
        for (int ii = 0; ii < 5; ++ii) {
            if (ii) __syncthreads();
            // store transposed: tt[c][b]; short2 along b (contiguous)
            unsigned short e00 = f2bf(acc[ii][0]);     // c=pc,   b=pb
            unsigned short e10 = f2bf(acc[ii][2]);     // c=pc,   b=pb+1
            unsigned short e01 = f2bf(acc[ii][1]);     // c=pc+1, b=pb
            unsigned short e11 = f2bf(acc[ii][3]);     // c=pc+1, b=pb+1
            *(unsigned int*)&tt[pc * 34 + pb]       = (unsigned int)e00 | ((unsigned int)e10 << 16);
            *(unsigned int*)&tt[(pc + 1) * 34 + pb] = (unsigned int)e01 | ((unsigned int)e11 << 16);
            __syncthreads();
            // coalesced write: row c0+rc, 4 shorts along b
            unsigned short o[4];
#pragma unroll
            for (int u = 0; u < 4; ++u) o[u] = tt[rc * 34 + rb4 + u];
            unsigned int lo = (unsigned int)o[0] | ((unsigned int)o[1] << 16);
            unsigned int hi = (unsigned int)o[2] | ((unsigned int)o[3] << 16);
            *(uint2*)&A1t[(size_t)(i0 + ii) * BC + (c0 + rc) * 256 + b0 + rb4] = make_uint2(lo, hi);
        }
    } else {
        const int idx = (bid - 512) * 256 + tid;       // 49152 float4 per matrix
        const float* src;
        unsigned short* dst;
        int off;
        if (idx < 49152) { src = f1; dst = f1b; off = idx; }
        else             { src = f2; dst = f2b; off = idx - 49152; }
        const float4 v = *(const float4*)&src[off * 4];
        const unsigned int lo = (unsigned int)f2bf(v.x) | ((unsigned int)f2bf(v.y) << 16);
        const unsigned int hi = (unsigned int)f2bf(v.z) | ((unsigned int)f2bf(v.w) << 16);
        *(uint2*)&dst[off * 4] = make_uint2(lo, hi);
    }
}

// ---------------- K2: flattened MFMA GEMM, 128x128 tile, BK=32 --------------
// A = f1b [j][b] (M=768,K=256), B^T = A1t flat [(i*256+c)][b] (N=10240,K=256)
// C de-flattened into A2[(i*768+j)*256 + c], bf16.
// m97 structure: 4 waves, wave tile 64x64 (4x4 16x16x32 frags), LDS [row][32].
__global__ __launch_bounds__(256) void k2_gemm(const unsigned short* __restrict__ f1b,
                                               const unsigned short* __restrict__ A1t,
                                               unsigned short* __restrict__ A2) {
    const int j0  = blockIdx.x * 128;   // M tile (j)
    const int cb0 = blockIdx.y * 128;   // N tile, flattened (i,c); 256%128==0 so one i per 128-col span... (i = col>>8 per column group of 256; cols within a 128-tile share i iff aligned -- they are, see epilogue)

    __shared__ unsigned short As[128 * 32];
    __shared__ unsigned short Bs[128 * 32];

    const int tid = threadIdx.x;
    const int lane = tid & 63, wave = tid >> 6;
    const int wm = (wave >> 1) * 64, wn = (wave & 1) * 64;
    const int l16 = lane & 15, q = lane >> 4;

    floatx4 acc[4][4];
#pragma unroll
    for (int p = 0; p < 4; ++p)
#pragma unroll
        for (int r = 0; r < 4; ++r) acc[p][r] = (floatx4)0.f;

    for (int kk = 0; kk < C_DIM; kk += 32) {
#pragma unroll
        for (int u = 0; u < 2; ++u) {
            const int chunk = (wave * 2 + u) * 64 + lane;   // 16B chunk id in tile
            const int row = chunk >> 2;                     // tile row
            const int sl  = (chunk & 3) * 8;                // k-slot (shorts)
            gl2lds16(&f1b[(j0 + row) * 256 + kk + sl],                 &As[(wave * 2 + u) * 512]);
            gl2lds16(&A1t[(size_t)(cb0 + row) * 256 + kk + sl],        &Bs[(wave * 2 + u) * 512]);
        }
        __syncthreads();
        short8 af[4], bf[4];
#pragma unroll
        for (int p = 0; p < 4; ++p) af[p] = *(const short8*)&As[(wm + p * 16 + l16) * 32 + q * 8];
#pragma unroll
        for (int r = 0; r < 4; ++r) bf[r] = *(const short8*)&Bs[(wn + r * 16 + l16) * 32 + q * 8];
#pragma unroll
        for (int p = 0; p < 4; ++p)
#pragma unroll
            for (int r = 0; r < 4; ++r)
                acc[p][r] = __builtin_amdgcn_mfma_f32_16x16x32_bf16(af[p], bf[r], acc[p][r], 0, 0, 0);
        __syncthreads();
    }
    // epilogue: col = cb0+wn+r*16+l16 is the flattened (i,c); i=col>>8, c=col&255.
    // Within one (r, fixed l16-range-16) group i is constant (16-aligned spans).
#pragma unroll
    for (int p = 0; p < 4; ++p)
#pragma unroll
        for (int r = 0; r < 4; ++r) {
            const int col = cb0 + wn + r * 16 + l16;
            const size_t base = (size_t)(col >> 8) * (768 * 256) + (size_t)(col & 255);
#pragma unroll
            for (int rr = 0; rr < 4; ++rr) {
                const int row = j0 + wm + p * 16 + q * 4 + rr;   // C: row=(lane>>4)*4+reg
                A2[base + (size_t)row * 256] = f2bf(acc[p][r][rr]);
            }
        }
}

// ---------------- K3: gathered MFMA GEMM, 128x128 tile, out f32 -------------
// A = gathered A2 rows [n][c] (M=8192,K=256), B^T = f2b [k][c] (N=768)
__global__ __launch_bounds__(256) void k3_gemm(const unsigned short* __restrict__ A2,
                                               const unsigned short* __restrict__ f2b,
                                               const int* __restrict__ ids,
                                               float* __restrict__ out) {
    const int n0 = blockIdx.x * 128;
    const int k0 = blockIdx.y * 128;

    __shared__ int ids_s[128];
    __shared__ unsigned short As[128 * 32];
    __shared__ unsigned short Bs[128 * 32];

    const int tid = threadIdx.x;
    if (tid < 128) ids_s[tid] = ids[n0 + tid];
    __syncthreads();

    const int lane = tid & 63, wave = tid >> 6;
    const int wm = (wave >> 1) * 64, wn = (wave & 1) * 64;
    const int l16 = lane & 15, q = lane >> 4;

    floatx4 acc[4][4];
#pragma unroll
    for (int p = 0; p < 4; ++p)
#pragma unroll
        for (int r = 0; r < 4; ++r) acc[p][r] = (floatx4)0.f;

    for (int kk = 0; kk < C_DIM; kk += 32) {
#pragma unroll
        for (int u = 0; u < 2; ++u) {
            const int chunk = (wave * 2 + u) * 64 + lane;
            const int row = chunk >> 2;
            const int sl  = (chunk & 3) * 8;
            gl2lds16(&A2[(size_t)ids_s[row] * 256 + kk + sl],   &As[(wave * 2 + u) * 512]);
            gl2lds16(&f2b[(k0 + row) * 256 + kk + sl],          &Bs[(wave * 2 + u) * 512]);
        }
        __syncthreads();
        short8 af[4], bf[4];
#pragma unroll
        for (int p = 0; p < 4; ++p) af[p] = *(const short8*)&As[(wm + p * 16 + l16) * 32 + q * 8];
#pragma unroll
        for (int r = 0; r < 4; ++r) bf[r] = *(const short8*)&Bs[(wn + r * 16 + l16) * 32 + q * 8];
#pragma unroll
        for (int p = 0; p < 4; ++p)
#pragma unroll
            for (int r = 0; r < 4; ++r)
                acc[p][r] = __builtin_amdgcn_mfma_f32_16x16x32_bf16(af[p], bf[r], acc[p][r], 0, 0, 0);
        __syncthreads();
    }
#pragma unroll
    for (int p = 0; p < 4; ++p)
#pragma unroll
        for (int r = 0; r < 4; ++r)
#pragma unroll
            for (int rr = 0; rr < 4; ++rr) {
                const int row = n0 + wm + p * 16 + q * 4 + rr;
                const int col = k0 + wn + r * 16 + l16;
                out[(size_t)row * HID + col] = acc[p][r][rr];
            }
}

extern "C" void kernel_launch(void* const* d_in, const int* in_sizes, int n_in,
                              void* d_out, int out_size, void* d_ws, size_t ws_size,
                              hipStream_t stream) {
    // inputs: 0=x(unused), 1=ids, 2=core, 3=f0, 4=f1, 5=f2
    const int*   ids  = (const int*)d_in[1];
    const float* core = (const float*)d_in[2];
    const float* f0   = (const float*)d_in[3];
    const float* f1   = (const float*)d_in[4];
    const float* f2   = (const float*)d_in[5];
    float* out = (float*)d_out;

    char* ws = (char*)d_ws;
    unsigned short* A1t = (unsigned short*)ws;                 //  5,242,880 B
    unsigned short* A2  = (unsigned short*)(ws + 5242880);     // 15,728,640 B
    unsigned short* f1b = (unsigned short*)(ws + 20971520);    //    393,216 B
    unsigned short* f2b = (unsigned short*)(ws + 21364736);    //    393,216 B

    k01_fused<<<896, 256, 0, stream>>>(core, f0, f1, f2, A1t, f1b, f2b);
    k2_gemm<<<dim3(6, 80), 256, 0, stream>>>(f1b, A1t, A2);
    k3_gemm<<<dim3(64, 6), 256, 0, stream>>>(A2, f2b, ids, out);
}